// Round 10
// baseline (176.977 us; speedup 1.0000x reference)
//
#include <hip/hip_runtime.h>
#include <hip/hip_cooperative_groups.h>

namespace cg = cooperative_groups;

#define N_NODES 600
#define NSUP    520
#define NQ      80
#define C_CLS   5
#define PER     104
#define F_IN    1024
#define EMBF    128
#define FE      256
#define CATD    261
#define CST     264
#define FCD     510
#define CONV_OUT 254  // FE - K + 1
#define R85     85    // 5 class reps + 80 queries
#define NBLK    170

__global__ __launch_bounds__(512) void mega_k(
    const float* __restrict__ f0,  const float* __restrict__ f1,
    const float* __restrict__ Wf0, const float* __restrict__ Wf1,
    const float* __restrict__ bf0, const float* __restrict__ bf1,
    const float* __restrict__ Win, const float* __restrict__ bin,
    const float* __restrict__ Wl,  const float* __restrict__ bl,
    const float* __restrict__ Wr,  const float* __restrict__ br,
    const float* __restrict__ att, const float* __restrict__ bgat,
    const float* __restrict__ cw,  const float* __restrict__ cb,
    const float* __restrict__ Wlab,const float* __restrict__ blab,
    float* __restrict__ csump, float* __restrict__ xrow85,
    float* __restrict__ gcnA,  float* __restrict__ hl85,
    float* __restrict__ hr85,  float* __restrict__ hlab,
    int* __restrict__ ctr,     float* __restrict__ out) {
    cg::grid_group grid = cg::this_grid();
    __shared__ float xs[F_IN];
    __shared__ float part[512];
    __shared__ float xrow[CATD + 3];
    __shared__ float es[R85 + 3], wsm[R85 + 3], go[FE], fcB[CONV_OUT + 2];
    __shared__ float red[2], hpart[8][C_CLS], sS[C_CLS], sQ[C_CLS];
    __shared__ int flag;
    const int gb = blockIdx.x, t = threadIdx.x;

    // ================= phase 0: partial class sums (blocks 0..39) =================
    if (gb == 0 && t == 0) *ctr = 0;
    if (gb < 40) {
        const int gtid = gb * 512 + t;              // 0..20479
        const int k    = gtid & 1023;
        const int rest = gtid >> 10;                // 0..19
        const int jh   = rest & 1;
        const int c    = (rest >> 1) % C_CLS;
        const int set  = rest / 10;
        const float* X = set ? f1 : f0;
        const float* p = X + (size_t)(c * PER + jh * 52) * F_IN + k;
        float acc = 0.f;
        for (int b = 0; b < 4; ++b) {
            float wv[13];
#pragma unroll
            for (int i = 0; i < 13; ++i) wv[i] = p[(size_t)(b * 13 + i) * F_IN];
#pragma unroll
            for (int i = 0; i < 13; ++i) acc += wv[i];
        }
        csump[((size_t)(set * 2 + jh) * C_CLS + c) * F_IN + k] = acc;
    }
    __threadfence();
    grid.sync();

    // ================= phase 1: embedding dot (blocks = r*2+set) =================
    {
        const int r = gb >> 1, set = gb & 1;
        const float* X = set ? f1 : f0;
        if (r < C_CLS) {
            const int k2 = t * 2;
            const float* cp0 = csump + ((size_t)(set * 2 + 0) * C_CLS + r) * F_IN;
            const float* cp1 = csump + ((size_t)(set * 2 + 1) * C_CLS + r) * F_IN;
            xs[k2]     = (cp0[k2]     + cp1[k2])     * (1.f / PER);
            xs[k2 + 1] = (cp0[k2 + 1] + cp1[k2 + 1]) * (1.f / PER);
        } else {
            const int q = NSUP + r - C_CLS;
            ((float2*)xs)[t] = ((const float2*)(X + (size_t)q * F_IN))[t];
        }
        __syncthreads();
        // 512 thr = 128 cols x 4 ksegs of 256
        const int col = t & 127, kseg = t >> 7;
        const float* W  = set ? Wf1 : Wf0;
        const float* Wp = W + (size_t)(kseg * 256) * EMBF + col;
        const float* xp = xs + kseg * 256;
        float acc = 0.f;
        for (int b = 0; b < 8; ++b) {
            float wv[32];
#pragma unroll
            for (int i = 0; i < 32; ++i) wv[i] = Wp[(size_t)(b * 32 + i) * EMBF];
#pragma unroll
            for (int i = 0; i < 32; ++i) acc += xp[b * 32 + i] * wv[i];
        }
        part[t] = acc;
        __syncthreads();
        if (t < 128) {
            float s = part[t] + part[t + 128] + part[t + 256] + part[t + 384];
            s += (set ? bf1[t] : bf0[t]);
            s = s > 0.f ? s : 0.01f * s;
            xrow85[r * CST + set * EMBF + t] = s;
        }
        if (set == 0 && t < C_CLS)
            xrow85[r * CST + FE + t] = (r < C_CLS) ? (t == r ? 1.f : 0.f) : 0.2f;
    }
    __threadfence();
    grid.sync();

    // ================= phase 2: 3 matmuls (blocks: r = gb%85, half = gb/85) ======
    {
        const int r = gb % R85, half = gb / R85;
        if (t < CATD) xrow[t] = xrow85[r * CST + t];
        __syncthreads();
        if (half == 0) {
            // mat0 (Win): 256 cols x 2 ksegs
            const int col = t & 255, kseg = t >> 8;
            const int k0 = kseg ? 131 : 0, k1 = kseg ? CATD : 131;
            const float* Wp = Win + col;
            float acc = 0.f;
            int k = k0;
            for (; k + 32 <= k1; k += 32) {
                float wv[32];
#pragma unroll
                for (int i = 0; i < 32; ++i) wv[i] = Wp[(size_t)(k + i) * FE];
#pragma unroll
                for (int i = 0; i < 32; ++i) acc += xrow[k + i] * wv[i];
            }
            for (; k < k1; ++k) acc += xrow[k] * Wp[(size_t)k * FE];
            part[t] = acc;
            __syncthreads();
            if (t < 256) {
                float v = part[t] + part[t + 256] + bin[t];
                v = v > 0.f ? v : 0.01f * v;
                gcnA[r * FE + t] = v;
            }
        } else {
            // mats 1,2 (Wl,Wr): col = t&255, mat = 1 + (t>>8), full K chain
            const int col = t & 255, mat = 1 + (t >> 8);
            const float* W = (mat == 1) ? Wl : Wr;
            const float* B = (mat == 1) ? bl : br;
            const float* Wp = W + col;
            float acc = 0.f;
            int k = 0;
            for (; k + 32 <= CATD; k += 32) {
                float wv[32];
#pragma unroll
                for (int i = 0; i < 32; ++i) wv[i] = Wp[(size_t)(k + i) * FE];
#pragma unroll
                for (int i = 0; i < 32; ++i) acc += xrow[k + i] * wv[i];
            }
            for (; k < CATD; ++k) acc += xrow[k] * Wp[(size_t)k * FE];
            float v = acc + B[col];
            if (mat == 1) hl85[r * FE + col] = v;
            else          hr85[r * FE + col] = v;
        }
    }
    __threadfence();
    grid.sync();

    // ================= phase 3: GAT + conv + label dot + pooling (blocks < 85) ===
    if (gb < R85) {
        const int ir = gb;
        const int lane = t & 63, w = t >> 6;
        float hrv[4], av[4];
#pragma unroll
        for (int p = 0; p < 4; ++p) {
            hrv[p] = hr85[ir * FE + p * 64 + lane];
            av[p]  = att[p * 64 + lane];
        }
        for (int jr = w; jr < R85; jr += 8) {
            float s = 0.f;
#pragma unroll
            for (int p = 0; p < 4; ++p) {
                float x = hl85[jr * FE + p * 64 + lane] + hrv[p];
                x = x > 0.f ? x : 0.2f * x;
                s += x * av[p];
            }
#pragma unroll
            for (int off = 32; off; off >>= 1) s += __shfl_xor(s, off);
            if (lane == 0) es[jr] = s;
        }
        __syncthreads();
        if (t < 64) {
            float m = es[t];
            if (t + 64 < R85) m = fmaxf(m, es[t + 64]);
#pragma unroll
            for (int off = 32; off; off >>= 1) m = fmaxf(m, __shfl_xor(m, off));
            if (t == 0) red[0] = m;
        }
        __syncthreads();
        const float m = red[0];
        if (t < R85) {
            // multiplicity: support dst ir<5: own class 1 (self-loop), others 104, queries 1.
            // query dst: classes 104, queries 1 (incl. self-loop).
            float n;
            if (ir < C_CLS) n = (t < C_CLS) ? (t == ir ? 1.f : 104.f) : 1.f;
            else            n = (t < C_CLS) ? 104.f : 1.f;
            wsm[t] = n * __expf(es[t] - m);
        }
        __syncthreads();
        if (t < 64) {
            float d = wsm[t] + ((t + 64 < R85) ? wsm[t + 64] : 0.f);
#pragma unroll
            for (int off = 32; off; off >>= 1) d += __shfl_xor(d, off);
            if (t == 0) red[1] = 1.f / d;
        }
        __syncthreads();
        const float inv = red[1];
        {
            const int f = t & 255, half = t >> 8;
            const int j0 = half ? 43 : 0, j1 = half ? R85 : 43;
            float acc = 0.f;
            int jr = j0;
            for (; jr + 8 <= j1; jr += 8) {
                float wv[8];
#pragma unroll
                for (int i = 0; i < 8; ++i) wv[i] = hl85[(jr + i) * FE + f];
#pragma unroll
                for (int i = 0; i < 8; ++i) acc += wsm[jr + i] * wv[i];
            }
            for (; jr < j1; ++jr) acc += wsm[jr] * hl85[jr * FE + f];
            part[t] = acc;
        }
        __syncthreads();
        if (t < FE) {
            float v = (part[t] + part[256 + t]) * inv + bgat[t];
            v = v > 0.f ? v : (__expf(v) - 1.f);   // elu
            go[t] = v;
        }
        __syncthreads();
        if (t < CONV_OUT)
            fcB[t] = 1.f / (1.f + __expf(-(go[t] * cw[0] + go[t + 1] * cw[1]
                                           + go[t + 2] * cw[2] + cb[0])));
        __syncthreads();
        {
            float a[C_CLS] = {0.f, 0.f, 0.f, 0.f, 0.f};
            if (t < FCD) {
                const float x = (t < FE) ? gcnA[ir * FE + t] : fcB[t - FE];
                const float* wl = Wlab + (size_t)t * C_CLS;
#pragma unroll
                for (int j = 0; j < C_CLS; ++j) a[j] = x * wl[j];
            }
#pragma unroll
            for (int j = 0; j < C_CLS; ++j) {
#pragma unroll
                for (int off = 32; off; off >>= 1) a[j] += __shfl_xor(a[j], off);
            }
            if (lane == 0) {
#pragma unroll
                for (int j = 0; j < C_CLS; ++j) hpart[w][j] = a[j];
            }
        }
        __syncthreads();
        if (t < C_CLS) {
            float s = 0.f;
#pragma unroll
            for (int ww = 0; ww < 8; ++ww) s += hpart[ww][t];
            hlab[ir * C_CLS + t] = s;
        }
        __syncthreads();
        __threadfence();
        if (t == 0) flag = (atomicAdd(ctr, 1) == R85 - 1) ? 1 : 0;
        __syncthreads();
        if (flag) {             // last finishing block: pooling + broadcast output
            __threadfence();
            if (t < C_CLS) {
                float s = 0.f;
                for (int cl = 0; cl < C_CLS; ++cl) s += hlab[cl * C_CLS + t];
                sS[t] = 104.f * s;                   // sum over 520 support rows
            } else if (t < 2 * C_CLS) {
                const int c = t - C_CLS;
                float s = 0.f;
                for (int q = 0; q < NQ; ++q) s += hlab[(C_CLS + q) * C_CLS + c];
                sQ[c] = s;                           // sum over 80 query rows
            }
            __syncthreads();
            const float rs = rsqrtf(81.f * 521.f);
            for (int idx = t; idx < N_NODES * C_CLS; idx += 512) {
                const int i = idx / C_CLS, c = idx - i * C_CLS;
                float v;
                if (i < NSUP) v = sQ[c] * rs + hlab[(i / PER) * C_CLS + c] * (1.0f / 81.0f);
                else          v = sS[c] * rs + hlab[(C_CLS + i - NSUP) * C_CLS + c] * (1.0f / 521.0f);
                out[idx] = v + blab[c];
            }
            if (t == 0) *ctr = 0;
        }
    }
}

extern "C" void kernel_launch(void* const* d_in, const int* in_sizes, int n_in,
                              void* d_out, int out_size, void* d_ws, size_t ws_size,
                              hipStream_t stream) {
    (void)in_sizes; (void)n_in; (void)out_size; (void)ws_size;
    const float* f0   = (const float*)d_in[0];
    const float* f1   = (const float*)d_in[1];
    const float* Wf0  = (const float*)d_in[9];
    const float* bf0  = (const float*)d_in[10];
    const float* Wf1  = (const float*)d_in[11];
    const float* bf1  = (const float*)d_in[12];
    const float* Win  = (const float*)d_in[13];
    const float* bin  = (const float*)d_in[14];
    const float* Wl   = (const float*)d_in[15];
    const float* bl   = (const float*)d_in[16];
    const float* Wr   = (const float*)d_in[17];
    const float* br   = (const float*)d_in[18];
    const float* att  = (const float*)d_in[19];
    const float* bgat = (const float*)d_in[20];
    const float* cw   = (const float*)d_in[21];
    const float* cb   = (const float*)d_in[22];
    const float* Wlab = (const float*)d_in[23];
    const float* blab = (const float*)d_in[24];
    float* out = (float*)d_out;

    float* ws = (float*)d_ws;
    float* gcnA   = ws;             // [85][256] = 21760
    float* hl85   = ws + 21760;     // [85][256]
    float* hr85   = ws + 43520;     // [85][256]
    float* csump  = ws + 65280;     // [2][2][5][1024] = 20480
    float* xrow85 = ws + 85760;     // [85][264] = 22440
    float* hlab   = ws + 108200;    // [85][5] = 425
    int*   ctr    = (int*)(ws + 108632);

    void* args[] = {
        (void*)&f0, (void*)&f1, (void*)&Wf0, (void*)&Wf1, (void*)&bf0, (void*)&bf1,
        (void*)&Win, (void*)&bin, (void*)&Wl, (void*)&bl, (void*)&Wr, (void*)&br,
        (void*)&att, (void*)&bgat, (void*)&cw, (void*)&cb, (void*)&Wlab, (void*)&blab,
        (void*)&csump, (void*)&xrow85, (void*)&gcnA, (void*)&hl85, (void*)&hr85,
        (void*)&hlab, (void*)&ctr, (void*)&out
    };
    hipLaunchCooperativeKernel((void*)mega_k, dim3(NBLK), dim3(512), args, 0, stream);
}

// Round 11
// 63.157 us; speedup vs baseline: 2.8022x; 2.8022x over previous
//
#include <hip/hip_runtime.h>

#define N_NODES 600
#define NSUP    520
#define NQ      80
#define C_CLS   5
#define PER     104
#define F_IN    1024
#define EMBF    128
#define FE      256
#define CATD    261
#define FCD     510
#define CONV_OUT 254  // FE - K + 1
#define R85     85    // 5 class reps + 80 queries

// K1: blocks 0..39: partial class sums (zeroes ctr too). blocks 40..119: L3 warm
// pass over all weights + query features (the harness poison wipes L2/L3 every
// replay; this converts row_k's cold ~900cy HBM chains into ~L3-hit chains).
__global__ __launch_bounds__(512) void csum_k(const float* __restrict__ f0,
                                              const float* __restrict__ f1,
                                              const float* __restrict__ Wf0,
                                              const float* __restrict__ Wf1,
                                              const float* __restrict__ Win,
                                              const float* __restrict__ Wl,
                                              const float* __restrict__ Wr,
                                              float* __restrict__ csump,
                                              int* __restrict__ ctr) {
    const int gb = blockIdx.x, t = threadIdx.x;
    if (gb == 0 && t == 0) *ctr = 0;
    if (gb < 40) {
        const int gtid = gb * 512 + t;              // 0..20479
        const int k    = gtid & 1023;
        const int rest = gtid >> 10;                // 0..19
        const int jh   = rest & 1;
        const int c    = (rest >> 1) % C_CLS;
        const int set  = rest / 10;
        const float* X = set ? f1 : f0;
        const float* p = X + (size_t)(c * PER + jh * 52) * F_IN + k;
        float acc = 0.f;
        for (int b = 0; b < 4; ++b) {
            float wv[13];
#pragma unroll
            for (int i = 0; i < 13; ++i) wv[i] = p[(size_t)(b * 13 + i) * F_IN];
#pragma unroll
            for (int i = 0; i < 13; ++i) acc += wv[i];
        }
        csump[((size_t)(set * 2 + jh) * C_CLS + c) * F_IN + k] = acc;
    } else {
        // warm: virtual concat of vec4 arrays:
        // Wf0 32768 | Wf1 32768 | Win 16704 | Wl 16704 | Wr 16704 | fq0 20480 | fq1 20480
        const int wt = (gb - 40) * 512 + t;         // 0..40959
        float acc = 0.f;
        for (int i = wt; i < 156608; i += 40960) {
            const float4* p;
            int j = i;
            if (j < 32768) p = (const float4*)Wf0 + j;
            else if ((j -= 32768) < 32768) p = (const float4*)Wf1 + j;
            else if ((j -= 32768) < 16704) p = (const float4*)Win + j;
            else if ((j -= 16704) < 16704) p = (const float4*)Wl + j;
            else if ((j -= 16704) < 16704) p = (const float4*)Wr + j;
            else if ((j -= 16704) < 20480) p = (const float4*)(f0 + (size_t)NSUP * F_IN) + j;
            else { j -= 20480; p = (const float4*)(f1 + (size_t)NSUP * F_IN) + j; }
            float4 v = *p;
            acc += v.x + v.y + v.z + v.w;
        }
        asm volatile("" :: "v"(acc));   // keep loads live (no DCE)
    }
}

// K2: per-row fused pipeline. grid 85, block 512. Double-buffered load batches.
__global__ __launch_bounds__(512) void row_k(
    const float* __restrict__ f0,  const float* __restrict__ f1,
    const float* __restrict__ csump,
    const float* __restrict__ Wf0, const float* __restrict__ Wf1,
    const float* __restrict__ bf0, const float* __restrict__ bf1,
    const float* __restrict__ Win, const float* __restrict__ bin,
    const float* __restrict__ Wl,  const float* __restrict__ bl,
    const float* __restrict__ Wr,  const float* __restrict__ br,
    float* __restrict__ gcnA, float* __restrict__ hl85, float* __restrict__ hr85) {
    __shared__ float xs[2][F_IN];
    __shared__ float xrow[CATD + 11];
    __shared__ float part[512];
    const int r = blockIdx.x, t = threadIdx.x;

    if (r < C_CLS) {
        const int k2 = t * 2;
#pragma unroll
        for (int set = 0; set < 2; ++set) {
            const float* cp0 = csump + ((size_t)(set * 2 + 0) * C_CLS + r) * F_IN;
            const float* cp1 = csump + ((size_t)(set * 2 + 1) * C_CLS + r) * F_IN;
            xs[set][k2]     = (cp0[k2]     + cp1[k2])     * (1.f / PER);
            xs[set][k2 + 1] = (cp0[k2 + 1] + cp1[k2 + 1]) * (1.f / PER);
        }
    } else {
        const int q = NSUP + r - C_CLS;
        if (t < 256) ((float4*)xs[0])[t]       = ((const float4*)(f0 + (size_t)q * F_IN))[t];
        else         ((float4*)xs[1])[t - 256] = ((const float4*)(f1 + (size_t)q * F_IN))[t - 256];
    }
    __syncthreads();

    // emb dot: f = t&127; half = t>>7 -> set = half>>1, kseg = half&1 (512 k's each)
    // 32 batches of 16, software-pipelined (a0/a1 ping-pong, static indices).
    {
        const int f = t & 127, half = t >> 7;
        const int set = half >> 1, kseg = half & 1;
        const float* W  = set ? Wf1 : Wf0;
        const float* Wp = W + (size_t)(kseg * 512) * EMBF + f;
        const float* xp = xs[set] + kseg * 512;
        float acc = 0.f;
        float a0[16], a1[16];
#pragma unroll
        for (int i = 0; i < 16; ++i) a0[i] = Wp[(size_t)i * EMBF];
        for (int b = 0; b < 16; ++b) {
            const int k0 = b * 32;
#pragma unroll
            for (int i = 0; i < 16; ++i) a1[i] = Wp[(size_t)(k0 + 16 + i) * EMBF];
#pragma unroll
            for (int i = 0; i < 16; ++i) acc += xp[k0 + i] * a0[i];
            if (b < 15) {
#pragma unroll
                for (int i = 0; i < 16; ++i) a0[i] = Wp[(size_t)(k0 + 32 + i) * EMBF];
            }
#pragma unroll
            for (int i = 0; i < 16; ++i) acc += xp[k0 + 16 + i] * a1[i];
        }
        part[t] = acc;
    }
    __syncthreads();
    if (t < 256) {
        const int f = t & 127, set = t >> 7;
        float s = part[set * 256 + f] + part[set * 256 + 128 + f];
        s += (set ? bf1[f] : bf0[f]);
        s = s > 0.f ? s : 0.01f * s;
        xrow[set * 128 + f] = s;
    }
    if (t < C_CLS) xrow[FE + t] = (r < C_CLS) ? (t == r ? 1.f : 0.f) : 0.2f;
    __syncthreads();

    // 3 matmuls: 768 (mat,col) units over 512 threads; 16 batches of 16 + 5 tail,
    // same double-buffer pipeline.
    for (int u = t; u < 768; u += 512) {
        const int mat = u >> 8, col = u & 255;
        const float* W = (mat == 0) ? Win : (mat == 1 ? Wl : Wr);
        const float* B = (mat == 0) ? bin : (mat == 1 ? bl : br);
        const float* Wp = W + col;
        float acc = 0.f;
        float a0[16], a1[16];
#pragma unroll
        for (int i = 0; i < 16; ++i) a0[i] = Wp[(size_t)i * FE];
        for (int b = 0; b < 8; ++b) {
            const int k0 = b * 32;
#pragma unroll
            for (int i = 0; i < 16; ++i) a1[i] = Wp[(size_t)(k0 + 16 + i) * FE];
#pragma unroll
            for (int i = 0; i < 16; ++i) acc += xrow[k0 + i] * a0[i];
            if (b < 7) {
#pragma unroll
                for (int i = 0; i < 16; ++i) a0[i] = Wp[(size_t)(k0 + 32 + i) * FE];
            }
#pragma unroll
            for (int i = 0; i < 16; ++i) acc += xrow[k0 + 16 + i] * a1[i];
        }
        {
            float wv[5];
#pragma unroll
            for (int i = 0; i < 5; ++i) wv[i] = Wp[(size_t)(256 + i) * FE];
#pragma unroll
            for (int i = 0; i < 5; ++i) acc += xrow[256 + i] * wv[i];
        }
        float v = acc + B[col];
        if (mat == 0) { v = v > 0.f ? v : 0.01f * v; gcnA[r * FE + col] = v; }
        else if (mat == 1) hl85[r * FE + col] = v;
        else               hr85[r * FE + col] = v;
    }
}

// K3: GATv2 row + conv + per-row label dot; last finishing block does pooling+output.
// grid 85, block 512.
__global__ __launch_bounds__(512) void gatfin_k(
    const float* __restrict__ hl85, const float* __restrict__ hr85,
    const float* __restrict__ att,  const float* __restrict__ bgat,
    const float* __restrict__ cw,   const float* __restrict__ cb,
    const float* __restrict__ gcnA, const float* __restrict__ Wlab,
    const float* __restrict__ blab,
    float* __restrict__ hlab, int* __restrict__ ctr, float* __restrict__ out) {
    __shared__ float es[R85 + 3], wsm[R85 + 3], go[FE], fcB[CONV_OUT + 2];
    __shared__ float part2[512], red[2], hpart[8][C_CLS];
    __shared__ float sS[C_CLS], sQ[C_CLS];
    __shared__ int flag;
    const int ir = blockIdx.x, t = threadIdx.x;
    const int lane = t & 63, w = t >> 6;

    float hrv[4], av[4];
#pragma unroll
    for (int p = 0; p < 4; ++p) {
        hrv[p] = hr85[ir * FE + p * 64 + lane];
        av[p]  = att[p * 64 + lane];
    }
    for (int jr = w; jr < R85; jr += 8) {
        float s = 0.f;
#pragma unroll
        for (int p = 0; p < 4; ++p) {
            float x = hl85[jr * FE + p * 64 + lane] + hrv[p];
            x = x > 0.f ? x : 0.2f * x;
            s += x * av[p];
        }
#pragma unroll
        for (int off = 32; off; off >>= 1) s += __shfl_xor(s, off);
        if (lane == 0) es[jr] = s;
    }
    __syncthreads();
    if (t < 64) {
        float m = es[t];
        if (t + 64 < R85) m = fmaxf(m, es[t + 64]);
#pragma unroll
        for (int off = 32; off; off >>= 1) m = fmaxf(m, __shfl_xor(m, off));
        if (t == 0) red[0] = m;
    }
    __syncthreads();
    const float m = red[0];
    if (t < R85) {
        // multiplicity: support dst ir<5: own class 1 (self-loop), other classes 104, queries 1.
        // query dst: classes 104, queries 1 (incl. self-loop).
        float n;
        if (ir < C_CLS) n = (t < C_CLS) ? (t == ir ? 1.f : 104.f) : 1.f;
        else            n = (t < C_CLS) ? 104.f : 1.f;
        wsm[t] = n * __expf(es[t] - m);
    }
    __syncthreads();
    if (t < 64) {
        float d = wsm[t] + ((t + 64 < R85) ? wsm[t + 64] : 0.f);
#pragma unroll
        for (int off = 32; off; off >>= 1) d += __shfl_xor(d, off);
        if (t == 0) red[1] = 1.f / d;
    }
    __syncthreads();
    const float inv = red[1];
    {
        const int f = t & 255, half = t >> 8;
        const int j0 = half ? 43 : 0, j1 = half ? R85 : 43;
        float acc = 0.f;
        int jr = j0;
        for (; jr + 8 <= j1; jr += 8) {
            float wv[8];
#pragma unroll
            for (int i = 0; i < 8; ++i) wv[i] = hl85[(jr + i) * FE + f];
#pragma unroll
            for (int i = 0; i < 8; ++i) acc += wsm[jr + i] * wv[i];
        }
        for (; jr < j1; ++jr) acc += wsm[jr] * hl85[jr * FE + f];
        part2[t] = acc;
    }
    __syncthreads();
    if (t < FE) {
        float v = (part2[t] + part2[256 + t]) * inv + bgat[t];
        v = v > 0.f ? v : (__expf(v) - 1.f);   // elu
        go[t] = v;
    }
    __syncthreads();
    if (t < CONV_OUT)
        fcB[t] = 1.f / (1.f + __expf(-(go[t] * cw[0] + go[t + 1] * cw[1]
                                       + go[t + 2] * cw[2] + cb[0])));
    __syncthreads();
    {
        float a[C_CLS] = {0.f, 0.f, 0.f, 0.f, 0.f};
        if (t < FCD) {
            const float x = (t < FE) ? gcnA[ir * FE + t] : fcB[t - FE];
            const float* wl = Wlab + (size_t)t * C_CLS;
#pragma unroll
            for (int j = 0; j < C_CLS; ++j) a[j] = x * wl[j];
        }
#pragma unroll
        for (int j = 0; j < C_CLS; ++j) {
#pragma unroll
            for (int off = 32; off; off >>= 1) a[j] += __shfl_xor(a[j], off);
        }
        if (lane == 0) {
#pragma unroll
            for (int j = 0; j < C_CLS; ++j) hpart[w][j] = a[j];
        }
    }
    __syncthreads();
    if (t < C_CLS) {
        float s = 0.f;
#pragma unroll
        for (int ww = 0; ww < 8; ++ww) s += hpart[ww][t];
        hlab[ir * C_CLS + t] = s;
    }
    __syncthreads();
    __threadfence();
    if (t == 0) flag = (atomicAdd(ctr, 1) == R85 - 1) ? 1 : 0;
    __syncthreads();
    if (flag) {               // last finishing block: pooling + broadcast output
        __threadfence();
        if (t < C_CLS) {
            float s = 0.f;
            for (int cl = 0; cl < C_CLS; ++cl) s += hlab[cl * C_CLS + t];
            sS[t] = 104.f * s;                       // sum over 520 support rows
        } else if (t < 2 * C_CLS) {
            const int c = t - C_CLS;
            float s = 0.f;
            for (int q = 0; q < NQ; ++q) s += hlab[(C_CLS + q) * C_CLS + c];
            sQ[c] = s;                               // sum over 80 query rows
        }
        __syncthreads();
        const float rs = rsqrtf(81.f * 521.f);
        for (int idx = t; idx < N_NODES * C_CLS; idx += 512) {
            const int i = idx / C_CLS, c = idx - i * C_CLS;
            float v;
            if (i < NSUP) v = sQ[c] * rs + hlab[(i / PER) * C_CLS + c] * (1.0f / 81.0f);
            else          v = sS[c] * rs + hlab[(C_CLS + i - NSUP) * C_CLS + c] * (1.0f / 521.0f);
            out[idx] = v + blab[c];
        }
        if (t == 0) *ctr = 0;   // reset for next replay
    }
}

extern "C" void kernel_launch(void* const* d_in, const int* in_sizes, int n_in,
                              void* d_out, int out_size, void* d_ws, size_t ws_size,
                              hipStream_t stream) {
    (void)in_sizes; (void)n_in; (void)out_size; (void)ws_size;
    const float* f0   = (const float*)d_in[0];
    const float* f1   = (const float*)d_in[1];
    const float* Wf0  = (const float*)d_in[9];
    const float* bf0  = (const float*)d_in[10];
    const float* Wf1  = (const float*)d_in[11];
    const float* bf1  = (const float*)d_in[12];
    const float* Win  = (const float*)d_in[13];
    const float* bin  = (const float*)d_in[14];
    const float* Wl   = (const float*)d_in[15];
    const float* bl   = (const float*)d_in[16];
    const float* Wr   = (const float*)d_in[17];
    const float* br   = (const float*)d_in[18];
    const float* att  = (const float*)d_in[19];
    const float* bgat = (const float*)d_in[20];
    const float* cw   = (const float*)d_in[21];
    const float* cb   = (const float*)d_in[22];
    const float* Wlab = (const float*)d_in[23];
    const float* blab = (const float*)d_in[24];
    float* out = (float*)d_out;

    float* ws = (float*)d_ws;
    float* gcnA  = ws;            // [85][256] = 21760
    float* hl85  = ws + 21760;    // [85][256]
    float* hr85  = ws + 43520;    // [85][256]
    float* csump = ws + 65280;    // [2][2][5][1024] = 20480
    float* hlab  = ws + 85760;    // [85][5] = 425
    int*   ctr   = (int*)(ws + 86208);

    csum_k  <<<120, 512, 0, stream>>>(f0, f1, Wf0, Wf1, Win, Wl, Wr, csump, ctr);
    row_k   <<<85, 512, 0, stream>>>(f0, f1, csump, Wf0, Wf1, bf0, bf1,
                                     Win, bin, Wl, bl, Wr, br, gcnA, hl85, hr85);
    gatfin_k<<<85, 512, 0, stream>>>(hl85, hr85, att, bgat, cw, cb,
                                     gcnA, Wlab, blab, hlab, ctr, out);
}

// Round 12
// 46.892 us; speedup vs baseline: 3.7741x; 1.3469x over previous
//
#include <hip/hip_runtime.h>

#define N_NODES 600
#define NSUP    520
#define NQ      80
#define C_CLS   5
#define PER     104
#define F_IN    1024
#define EMBF    128
#define FE      256
#define CATD    261
#define CST     264   // stride of xrow85
#define FCD     510
#define CONV_OUT 254  // FE - K + 1
#define R85     85    // 5 class reps + 80 queries

// K1: blocks 0..39 csum partials (+ctr zero); 40..199 full QUERY embeddings
// (query rows don't depend on csum); 200..215 warm Win/Wl/Wr into L3.
__global__ __launch_bounds__(512) void k1_k(const float* __restrict__ f0,
                                            const float* __restrict__ f1,
                                            const float* __restrict__ Wf0,
                                            const float* __restrict__ Wf1,
                                            const float* __restrict__ bf0,
                                            const float* __restrict__ bf1,
                                            const float* __restrict__ Win,
                                            const float* __restrict__ Wl,
                                            const float* __restrict__ Wr,
                                            float* __restrict__ csump,
                                            float* __restrict__ xrow85,
                                            int* __restrict__ ctr) {
    __shared__ float xs[F_IN];
    __shared__ float part[512];
    const int gb = blockIdx.x, t = threadIdx.x;
    if (gb == 0 && t == 0) *ctr = 0;
    if (gb < 40) {
        const int gtid = gb * 512 + t;              // 0..20479
        const int k    = gtid & 1023;
        const int rest = gtid >> 10;                // 0..19
        const int jh   = rest & 1;
        const int c    = (rest >> 1) % C_CLS;
        const int set  = rest / 10;
        const float* X = set ? f1 : f0;
        const float* p = X + (size_t)(c * PER + jh * 52) * F_IN + k;
        float acc = 0.f;
        for (int b = 0; b < 4; ++b) {
            float wv[13];
#pragma unroll
            for (int i = 0; i < 13; ++i) wv[i] = p[(size_t)(b * 13 + i) * F_IN];
#pragma unroll
            for (int i = 0; i < 13; ++i) acc += wv[i];
        }
        csump[((size_t)(set * 2 + jh) * C_CLS + c) * F_IN + k] = acc;
    } else if (gb < 200) {
        // query embedding, complete: idx -> (q, set)
        const int idx = gb - 40, q = idx >> 1, set = idx & 1;
        const float* X = set ? f1 : f0;
        const float* W = set ? Wf1 : Wf0;
        ((float2*)xs)[t] = ((const float2*)(X + (size_t)(NSUP + q) * F_IN))[t];
        __syncthreads();
        const int col = t & 127, kseg = t >> 7;     // 128 cols x 4 ksegs of 256
        const float* Wp = W + (size_t)(kseg * 256) * EMBF + col;
        const float* xp = xs + kseg * 256;
        float acc = 0.f;
        for (int b = 0; b < 8; ++b) {
            float wv[32];
#pragma unroll
            for (int i = 0; i < 32; ++i) wv[i] = Wp[(size_t)(b * 32 + i) * EMBF];
#pragma unroll
            for (int i = 0; i < 32; ++i) acc += xp[b * 32 + i] * wv[i];
        }
        part[t] = acc;
        __syncthreads();
        const int r = C_CLS + q;
        if (t < 128) {
            float s = part[t] + part[t + 128] + part[t + 256] + part[t + 384];
            s += (set ? bf1[t] : bf0[t]);
            s = s > 0.f ? s : 0.01f * s;
            xrow85[r * CST + set * EMBF + t] = s;
        }
        if (set == 0 && t < C_CLS) xrow85[r * CST + FE + t] = 0.2f;
    } else {
        // warm Win/Wl/Wr (L3) for K3
        const int wt = (gb - 200) * 512 + t;        // 0..8191
        float acc = 0.f;
        for (int i = wt; i < 16704 * 3; i += 8192) {
            const float4* p;
            int j = i;
            if (j < 16704) p = (const float4*)Win + j;
            else if ((j -= 16704) < 16704) p = (const float4*)Wl + j;
            else { j -= 16704; p = (const float4*)Wr + j; }
            float4 v = *p;
            acc += v.x + v.y + v.z + v.w;
        }
        asm volatile("" :: "v"(acc));
    }
}

// K2: rep embeddings. grid (5 reps, 2 sets), block 512.
__global__ __launch_bounds__(512) void k2_k(const float* __restrict__ csump,
                                            const float* __restrict__ Wf0,
                                            const float* __restrict__ Wf1,
                                            const float* __restrict__ bf0,
                                            const float* __restrict__ bf1,
                                            float* __restrict__ xrow85) {
    __shared__ float xs[F_IN];
    __shared__ float part[512];
    const int r = blockIdx.x, set = blockIdx.y, t = threadIdx.x;
    const int k2 = t * 2;
    const float* cp0 = csump + ((size_t)(set * 2 + 0) * C_CLS + r) * F_IN;
    const float* cp1 = csump + ((size_t)(set * 2 + 1) * C_CLS + r) * F_IN;
    xs[k2]     = (cp0[k2]     + cp1[k2])     * (1.f / PER);
    xs[k2 + 1] = (cp0[k2 + 1] + cp1[k2 + 1]) * (1.f / PER);
    __syncthreads();
    const int col = t & 127, kseg = t >> 7;
    const float* W  = set ? Wf1 : Wf0;
    const float* Wp = W + (size_t)(kseg * 256) * EMBF + col;
    const float* xp = xs + kseg * 256;
    float acc = 0.f;
    for (int b = 0; b < 8; ++b) {
        float wv[32];
#pragma unroll
        for (int i = 0; i < 32; ++i) wv[i] = Wp[(size_t)(b * 32 + i) * EMBF];
#pragma unroll
        for (int i = 0; i < 32; ++i) acc += xp[b * 32 + i] * wv[i];
    }
    part[t] = acc;
    __syncthreads();
    if (t < 128) {
        float s = part[t] + part[t + 128] + part[t + 256] + part[t + 384];
        s += (set ? bf1[t] : bf0[t]);
        s = s > 0.f ? s : 0.01f * s;
        xrow85[r * CST + set * EMBF + t] = s;
    }
    if (set == 0 && t < C_CLS) xrow85[r * CST + FE + t] = (t == r) ? 1.f : 0.f;
}

// K3: three matmuls. grid (85 rows, 3 mats), block 512 = 256 cols x 2 k-halves.
__global__ __launch_bounds__(512) void k3_k(const float* __restrict__ xrow85,
                                            const float* __restrict__ Win,
                                            const float* __restrict__ bin,
                                            const float* __restrict__ Wl,
                                            const float* __restrict__ bl,
                                            const float* __restrict__ Wr,
                                            const float* __restrict__ br,
                                            float* __restrict__ gcnA,
                                            float* __restrict__ hl85,
                                            float* __restrict__ hr85) {
    __shared__ float xrow[CATD + 3];
    __shared__ float part[512];
    const int r = blockIdx.x, mat = blockIdx.y, t = threadIdx.x;
    if (t < CATD) xrow[t] = xrow85[r * CST + t];
    __syncthreads();
    const float* W = (mat == 0) ? Win : (mat == 1 ? Wl : Wr);
    const float* B = (mat == 0) ? bin : (mat == 1 ? bl : br);
    const int col = t & 255, kh = t >> 8;
    const int k0 = kh ? 131 : 0, k1 = kh ? CATD : 131;
    const float* Wp = W + col;
    float acc = 0.f;
    int k = k0;
    for (; k + 32 <= k1; k += 32) {
        float wv[32];
#pragma unroll
        for (int i = 0; i < 32; ++i) wv[i] = Wp[(size_t)(k + i) * FE];
#pragma unroll
        for (int i = 0; i < 32; ++i) acc += xrow[k + i] * wv[i];
    }
    for (; k < k1; ++k) acc += xrow[k] * Wp[(size_t)k * FE];
    part[t] = acc;
    __syncthreads();
    if (t < 256) {
        float v = part[t] + part[t + 256] + B[t];
        if (mat == 0) { v = v > 0.f ? v : 0.01f * v; gcnA[r * FE + t] = v; }
        else if (mat == 1) hl85[r * FE + t] = v;
        else              hr85[r * FE + t] = v;
    }
}

// K4: GATv2 row + conv + label dot; last finishing block does pooling + output.
__global__ __launch_bounds__(512) void gatfin_k(
    const float* __restrict__ hl85, const float* __restrict__ hr85,
    const float* __restrict__ att,  const float* __restrict__ bgat,
    const float* __restrict__ cw,   const float* __restrict__ cb,
    const float* __restrict__ gcnA, const float* __restrict__ Wlab,
    const float* __restrict__ blab,
    float* __restrict__ hlab, int* __restrict__ ctr, float* __restrict__ out) {
    __shared__ float es[R85 + 3], wsm[R85 + 3], go[FE], fcB[CONV_OUT + 2];
    __shared__ float part2[512], red[2], hpart[8][C_CLS];
    __shared__ float sS[C_CLS], sQ[C_CLS];
    __shared__ int flag;
    const int ir = blockIdx.x, t = threadIdx.x;
    const int lane = t & 63, w = t >> 6;

    float hrv[4], av[4];
#pragma unroll
    for (int p = 0; p < 4; ++p) {
        hrv[p] = hr85[ir * FE + p * 64 + lane];
        av[p]  = att[p * 64 + lane];
    }
    for (int jr = w; jr < R85; jr += 8) {
        float s = 0.f;
#pragma unroll
        for (int p = 0; p < 4; ++p) {
            float x = hl85[jr * FE + p * 64 + lane] + hrv[p];
            x = x > 0.f ? x : 0.2f * x;
            s += x * av[p];
        }
#pragma unroll
        for (int off = 32; off; off >>= 1) s += __shfl_xor(s, off);
        if (lane == 0) es[jr] = s;
    }
    __syncthreads();
    if (t < 64) {
        float m = es[t];
        if (t + 64 < R85) m = fmaxf(m, es[t + 64]);
#pragma unroll
        for (int off = 32; off; off >>= 1) m = fmaxf(m, __shfl_xor(m, off));
        if (t == 0) red[0] = m;
    }
    __syncthreads();
    const float m = red[0];
    if (t < R85) {
        // multiplicity: support dst ir<5: own class 1 (self-loop), other classes 104, queries 1.
        // query dst: classes 104, queries 1 (incl. self-loop).
        float n;
        if (ir < C_CLS) n = (t < C_CLS) ? (t == ir ? 1.f : 104.f) : 1.f;
        else            n = (t < C_CLS) ? 104.f : 1.f;
        wsm[t] = n * __expf(es[t] - m);
    }
    __syncthreads();
    if (t < 64) {
        float d = wsm[t] + ((t + 64 < R85) ? wsm[t + 64] : 0.f);
#pragma unroll
        for (int off = 32; off; off >>= 1) d += __shfl_xor(d, off);
        if (t == 0) red[1] = 1.f / d;
    }
    __syncthreads();
    const float inv = red[1];
    {
        const int f = t & 255, half = t >> 8;
        const int j0 = half ? 43 : 0, j1 = half ? R85 : 43;
        float acc = 0.f;
        int jr = j0;
        for (; jr + 8 <= j1; jr += 8) {
            float wv[8];
#pragma unroll
            for (int i = 0; i < 8; ++i) wv[i] = hl85[(jr + i) * FE + f];
#pragma unroll
            for (int i = 0; i < 8; ++i) acc += wsm[jr + i] * wv[i];
        }
        for (; jr < j1; ++jr) acc += wsm[jr] * hl85[jr * FE + f];
        part2[t] = acc;
    }
    __syncthreads();
    if (t < FE) {
        float v = (part2[t] + part2[256 + t]) * inv + bgat[t];
        v = v > 0.f ? v : (__expf(v) - 1.f);   // elu
        go[t] = v;
    }
    __syncthreads();
    if (t < CONV_OUT)
        fcB[t] = 1.f / (1.f + __expf(-(go[t] * cw[0] + go[t + 1] * cw[1]
                                       + go[t + 2] * cw[2] + cb[0])));
    __syncthreads();
    {
        float a[C_CLS] = {0.f, 0.f, 0.f, 0.f, 0.f};
        if (t < FCD) {
            const float x = (t < FE) ? gcnA[ir * FE + t] : fcB[t - FE];
            const float* wl = Wlab + (size_t)t * C_CLS;
#pragma unroll
            for (int j = 0; j < C_CLS; ++j) a[j] = x * wl[j];
        }
#pragma unroll
        for (int j = 0; j < C_CLS; ++j) {
#pragma unroll
            for (int off = 32; off; off >>= 1) a[j] += __shfl_xor(a[j], off);
        }
        if (lane == 0) {
#pragma unroll
            for (int j = 0; j < C_CLS; ++j) hpart[w][j] = a[j];
        }
    }
    __syncthreads();
    if (t < C_CLS) {
        float s = 0.f;
#pragma unroll
        for (int ww = 0; ww < 8; ++ww) s += hpart[ww][t];
        hlab[ir * C_CLS + t] = s;
    }
    __syncthreads();
    __threadfence();
    if (t == 0) flag = (atomicAdd(ctr, 1) == R85 - 1) ? 1 : 0;
    __syncthreads();
    if (flag) {               // last finishing block: pooling + broadcast output
        __threadfence();
        if (t < C_CLS) {
            float s = 0.f;
            for (int cl = 0; cl < C_CLS; ++cl) s += hlab[cl * C_CLS + t];
            sS[t] = 104.f * s;                       // sum over 520 support rows
        } else if (t < 2 * C_CLS) {
            const int c = t - C_CLS;
            float s = 0.f;
            for (int q = 0; q < NQ; ++q) s += hlab[(C_CLS + q) * C_CLS + c];
            sQ[c] = s;                               // sum over 80 query rows
        }
        __syncthreads();
        const float rs = rsqrtf(81.f * 521.f);
        for (int idx = t; idx < N_NODES * C_CLS; idx += 512) {
            const int i = idx / C_CLS, c = idx - i * C_CLS;
            float v;
            if (i < NSUP) v = sQ[c] * rs + hlab[(i / PER) * C_CLS + c] * (1.0f / 81.0f);
            else          v = sS[c] * rs + hlab[(C_CLS + i - NSUP) * C_CLS + c] * (1.0f / 521.0f);
            out[idx] = v + blab[c];
        }
        if (t == 0) *ctr = 0;   // reset for next replay
    }
}

extern "C" void kernel_launch(void* const* d_in, const int* in_sizes, int n_in,
                              void* d_out, int out_size, void* d_ws, size_t ws_size,
                              hipStream_t stream) {
    (void)in_sizes; (void)n_in; (void)out_size; (void)ws_size;
    const float* f0   = (const float*)d_in[0];
    const float* f1   = (const float*)d_in[1];
    const float* Wf0  = (const float*)d_in[9];
    const float* bf0  = (const float*)d_in[10];
    const float* Wf1  = (const float*)d_in[11];
    const float* bf1  = (const float*)d_in[12];
    const float* Win  = (const float*)d_in[13];
    const float* bin  = (const float*)d_in[14];
    const float* Wl   = (const float*)d_in[15];
    const float* bl   = (const float*)d_in[16];
    const float* Wr   = (const float*)d_in[17];
    const float* br   = (const float*)d_in[18];
    const float* att  = (const float*)d_in[19];
    const float* bgat = (const float*)d_in[20];
    const float* cw   = (const float*)d_in[21];
    const float* cb   = (const float*)d_in[22];
    const float* Wlab = (const float*)d_in[23];
    const float* blab = (const float*)d_in[24];
    float* out = (float*)d_out;

    float* ws = (float*)d_ws;
    float* gcnA   = ws;             // [85][256] = 21760
    float* hl85   = ws + 21760;     // [85][256]
    float* hr85   = ws + 43520;     // [85][256]
    float* csump  = ws + 65280;     // [2][2][5][1024] = 20480
    float* xrow85 = ws + 85760;     // [85][264] = 22440
    float* hlab   = ws + 108200;    // [85][5]
    int*   ctr    = (int*)(ws + 108640);

    k1_k    <<<216, 512, 0, stream>>>(f0, f1, Wf0, Wf1, bf0, bf1, Win, Wl, Wr,
                                      csump, xrow85, ctr);
    k2_k    <<<dim3(5, 2), 512, 0, stream>>>(csump, Wf0, Wf1, bf0, bf1, xrow85);
    k3_k    <<<dim3(85, 3), 512, 0, stream>>>(xrow85, Win, bin, Wl, bl, Wr, br,
                                              gcnA, hl85, hr85);
    gatfin_k<<<85, 512, 0, stream>>>(hl85, hr85, att, bgat, cw, cb,
                                     gcnA, Wlab, blab, hlab, ctr, out);
}